// Round 1
// baseline (1496.114 us; speedup 1.0000x reference)
//
#include <hip/hip_runtime.h>
#include <hip/hip_bf16.h>

typedef unsigned short u16;
typedef __bf16 bf16x8 __attribute__((ext_vector_type(8)));
typedef float f32x4 __attribute__((ext_vector_type(4)));

#define N_HEADS 32
#define HD 128
#define HIDDEN 4096

__device__ __forceinline__ u16 f2bf(float x) {
    union { float f; unsigned u; } v; v.f = x;
    unsigned r = v.u + 0x7fffu + ((v.u >> 16) & 1u);
    return (u16)(r >> 16);
}
__device__ __forceinline__ float bf2f(u16 x) {
    return __uint_as_float((unsigned)x << 16);
}
__device__ __forceinline__ void gload_lds16(const void* g, void* l) {
    __builtin_amdgcn_global_load_lds(
        (const __attribute__((address_space(1))) unsigned*)g,
        (__attribute__((address_space(3))) unsigned*)l, 16, 0, 0);
}

// ---------------------------------------------------------------- cast kernel
__global__ __launch_bounds__(256) void cast_kernel(
    const float* __restrict__ Wq, const float* __restrict__ Wk,
    const float* __restrict__ Wv, const float* __restrict__ Wo,
    const float* __restrict__ H,
    const float* __restrict__ bq, const float* __restrict__ bk,
    const float* __restrict__ bv,
    u16* __restrict__ wsW, u16* __restrict__ wsWo, u16* __restrict__ wsH,
    float* __restrict__ wsB, long hsz)
{
    const long WSZ = (long)HIDDEN * HIDDEN;         // 16.78M
    long total4 = (WSZ * 4 + hsz) >> 2;
    for (long i = (long)blockIdx.x * blockDim.x + threadIdx.x; i < total4;
         i += (long)gridDim.x * blockDim.x) {
        long e = i << 2;
        const float* src; u16* dst;
        if (e < WSZ)            { src = Wq + e;           dst = wsW + e; }
        else if (e < 2*WSZ)     { src = Wk + (e - WSZ);   dst = wsW + e; }
        else if (e < 3*WSZ)     { src = Wv + (e - 2*WSZ); dst = wsW + e; }
        else if (e < 4*WSZ)     { src = Wo + (e - 3*WSZ); dst = wsWo + (e - 3*WSZ); }
        else                    { src = H  + (e - 4*WSZ); dst = wsH  + (e - 4*WSZ); }
        float4 v = *(const float4*)src;
        ushort4 o; o.x = f2bf(v.x); o.y = f2bf(v.y); o.z = f2bf(v.z); o.w = f2bf(v.w);
        *(ushort4*)dst = o;
    }
    for (int i = blockIdx.x * blockDim.x + threadIdx.x; i < 3 * HIDDEN;
         i += gridDim.x * blockDim.x) {
        wsB[i] = (i < HIDDEN) ? bq[i] : (i < 2*HIDDEN ? bk[i - HIDDEN] : bv[i - 2*HIDDEN]);
    }
}

// ------------------------------------------------- GEMM: C[M,N] = A @ Bt^T + bias
// A bf16 [M,K], Bt bf16 [N,K] (row n = output feature), out fp32 or bf16.
__global__ __launch_bounds__(256) void gemm_bt(
    const u16* __restrict__ A, const u16* __restrict__ Bt,
    const float* __restrict__ bias, void* __restrict__ Cout,
    int M, int N, int K, int out_bf16)
{
    __shared__ u16 As[128 * 32];   // [row][32k], 64B rows
    __shared__ u16 Bs[128 * 32];
    const int tid = threadIdx.x;
    const int w = tid >> 6, lane = tid & 63;
    const int qd = lane >> 4, l15 = lane & 15;
    const int bm = blockIdx.x, bn = blockIdx.y;
    const int wm = w >> 1, wn = w & 1;
    f32x4 acc[4][4] = {};
    const int srow = lane >> 2;          // 0..15
    const int scol = (lane & 3) * 8;     // k elem offset
    const long Ar = (long)bm * 128 + w * 32 + srow;
    const long Br = (long)bn * 128 + w * 32 + srow;
    for (int k0 = 0; k0 < K; k0 += 32) {
        __syncthreads();
        gload_lds16(A  + Ar * K        + k0 + scol, (char*)As + (w*32     ) * 64);
        gload_lds16(A  + (Ar + 16) * K + k0 + scol, (char*)As + (w*32 + 16) * 64);
        gload_lds16(Bt + Br * K        + k0 + scol, (char*)Bs + (w*32     ) * 64);
        gload_lds16(Bt + (Br + 16) * K + k0 + scol, (char*)Bs + (w*32 + 16) * 64);
        __syncthreads();
        bf16x8 a[4], b[4];
#pragma unroll
        for (int mt = 0; mt < 4; mt++)
            a[mt] = *(const bf16x8*)&As[(wm*64 + mt*16 + l15) * 32 + qd * 8];
#pragma unroll
        for (int nt = 0; nt < 4; nt++)
            b[nt] = *(const bf16x8*)&Bs[(wn*64 + nt*16 + l15) * 32 + qd * 8];
#pragma unroll
        for (int mt = 0; mt < 4; mt++)
#pragma unroll
            for (int nt = 0; nt < 4; nt++)
                acc[mt][nt] = __builtin_amdgcn_mfma_f32_16x16x32_bf16(
                    a[mt], b[nt], acc[mt][nt], 0, 0, 0);
    }
#pragma unroll
    for (int nt = 0; nt < 4; nt++) {
        int n = bn*128 + wn*64 + nt*16 + l15;
        float bv = bias[n];
#pragma unroll
        for (int mt = 0; mt < 4; mt++) {
            int m0 = bm*128 + wm*64 + mt*16 + qd*4;
#pragma unroll
            for (int r = 0; r < 4; r++) {
                float v = acc[mt][nt][r] + bv;
                if (out_bf16) ((u16*)Cout)[(long)(m0 + r) * N + n] = f2bf(v);
                else          ((float*)Cout)[(long)(m0 + r) * N + n] = v;
            }
        }
    }
}

// ------------------------------------------------------------- RoPE + KV scatter
__global__ __launch_bounds__(256) void rope_scatter(
    const u16* __restrict__ qkv, const int* __restrict__ pos_ids,
    const int* __restrict__ q_start, const int* __restrict__ q_lens,
    const int* __restrict__ kv_lens, const int* __restrict__ blk_off,
    float* __restrict__ pk, float* __restrict__ pv, u16* __restrict__ qr,
    int Bn, int maxb)
{
    int t = blockIdx.x >> 3;
    int h = ((blockIdx.x & 7) << 2) + (threadIdx.x >> 6);
    int d = threadIdx.x & 63;
    int b = 0;
    for (int i = 1; i < Bn; i++) if (t >= q_start[i]) b = i;
    int pos = pos_ids[t];
    float inv = exp2f(-(float)d * (13.287712379549449f / 64.0f)); // 10000^(-d/64)
    float f = (float)pos * inv;
    float cs = cosf(f), sn = sinf(f);
    const u16* row = qkv + (long)t * (3 * HIDDEN);
    float q1 = bf2f(row[h*HD + d]);
    float q2 = bf2f(row[h*HD + d + 64]);
    long qbase = ((long)t * N_HEADS + h) * HD + d;
    qr[qbase]      = f2bf(q1 * cs - q2 * sn);
    qr[qbase + 64] = f2bf(q2 * cs + q1 * sn);
    float k1 = bf2f(row[HIDDEN + h*HD + d]);
    float k2 = bf2f(row[HIDDEN + h*HD + d + 64]);
    float v1 = bf2f(row[2*HIDDEN + h*HD + d]);
    float v2 = bf2f(row[2*HIDDEN + h*HD + d + 64]);
    int kvpos = kv_lens[b] - q_lens[b] + (t - q_start[b]);
    int blk = blk_off[b * maxb + (kvpos >> 6)];
    int off = kvpos & 63;
    long base = (((long)blk * 64 + off) * N_HEADS + h) * HD + d;
    pk[base]      = k1 * cs - k2 * sn;
    pk[base + 64] = k2 * cs + k1 * sn;
    pv[base]      = v1;
    pv[base + 64] = v2;
}

// ----------------------------------------------------- flash attention (paged KV)
__global__ __launch_bounds__(256) void attn_kernel(
    const u16* __restrict__ Qr, const float* __restrict__ pk,
    const float* __restrict__ pv,
    const int* __restrict__ q_start, const int* __restrict__ q_lens,
    const int* __restrict__ kv_lens, const int* __restrict__ blk_off,
    u16* __restrict__ aout, int Bn, int maxb, int ntiles)
{
    __shared__ u16 Qs[4 * 64 * 32];     // [kstep][qrow][32d]
    __shared__ u16 Ks[4 * 64 * 32];     // [kstep][key][32d]
    __shared__ u16 Vt[2 * 128 * 32];    // [kstep2][d][32key]  (V transposed)
    __shared__ u16 Ps[4 * 2 * 16 * 32]; // [wave][kstep2][m][32key]
    int tile = blockIdx.x % ntiles;
    int h    = blockIdx.x / ntiles;
    int b = 0, q0 = 0, acc = 0;
    for (int i = 0; i < Bn; i++) {
        int nt = q_lens[i] >> 6;
        if (tile >= acc && tile < acc + nt) { b = i; q0 = (tile - acc) << 6; }
        acc += nt;
    }
    int hist = kv_lens[b] - q_lens[b];
    int tok0 = q_start[b] + q0;
    int nchunk = ((hist + q0) >> 6) + 1;
    const int tid = threadIdx.x, w = tid >> 6, lane = tid & 63;
    const int qd = lane >> 4, l15 = lane & 15;

    // stage Q tile (64 x 128) once
    for (int i = 0; i < 8; i++) {
        int idx = i * 1024 + tid * 4;
        int row = idx >> 7, d = idx & 127;
        const u16* src = Qr + ((long)(tok0 + row) * N_HEADS + h) * HD + d;
        uint2 v = *(const uint2*)src;
        *(uint2*)&Qs[(d >> 5) * 2048 + row * 32 + (d & 31)] = v;
    }
    float mstate[4], lstate[4];
    f32x4 o[8];
#pragma unroll
    for (int r = 0; r < 4; r++) { mstate[r] = -1e30f; lstate[r] = 0.f; }
#pragma unroll
    for (int dt = 0; dt < 8; dt++) o[dt] = (f32x4){0.f, 0.f, 0.f, 0.f};
    const float scale = 0.08838834764831845f;

    for (int c = 0; c < nchunk; c++) {
        int blk = blk_off[b * maxb + c];
        const float* kb = pk + ((long)blk * 64 * N_HEADS + h) * HD;
        const float* vb = pv + ((long)blk * 64 * N_HEADS + h) * HD;
        __syncthreads();               // prev compute done (also covers Q stage)
        for (int i = 0; i < 8; i++) {  // K: natural layout
            int idx = i * 1024 + tid * 4;
            int key = idx >> 7, d = idx & 127;
            float4 k4 = *(const float4*)(kb + (long)key * (N_HEADS * HD) + d);
            ushort4 o4; o4.x = f2bf(k4.x); o4.y = f2bf(k4.y);
            o4.z = f2bf(k4.z); o4.w = f2bf(k4.w);
            *(ushort4*)&Ks[(d >> 5) * 2048 + key * 32 + (d & 31)] = o4;
        }
        {
            int key = tid >> 2;        // V: transposed layout
            int ks2 = key >> 5, k32 = key & 31;
            for (int i = 0; i < 8; i++) {
                int d = ((tid & 3) << 2) + (i << 4);
                float4 v4 = *(const float4*)(vb + (long)key * (N_HEADS * HD) + d);
                Vt[ks2 * 4096 + (d + 0) * 32 + k32] = f2bf(v4.x);
                Vt[ks2 * 4096 + (d + 1) * 32 + k32] = f2bf(v4.y);
                Vt[ks2 * 4096 + (d + 2) * 32 + k32] = f2bf(v4.z);
                Vt[ks2 * 4096 + (d + 3) * 32 + k32] = f2bf(v4.w);
            }
        }
        __syncthreads();
        // S = Q K^T (wave w: q rows w*16..w*16+15)
        f32x4 s[4] = {};
#pragma unroll
        for (int ks = 0; ks < 4; ks++) {
            bf16x8 aq = *(const bf16x8*)&Qs[ks * 2048 + (w * 16 + l15) * 32 + qd * 8];
#pragma unroll
            for (int nt = 0; nt < 4; nt++) {
                bf16x8 bk = *(const bf16x8*)&Ks[ks * 2048 + (nt * 16 + l15) * 32 + qd * 8];
                s[nt] = __builtin_amdgcn_mfma_f32_16x16x32_bf16(aq, bk, s[nt], 0, 0, 0);
            }
        }
        int rowbase = q0 + w * 16 + qd * 4;   // + r = local query pos
        int keybase = c * 64;
        bool needmask = (keybase + 63) > (hist + q0 + w * 16);
        float p[4][4];
#pragma unroll
        for (int r = 0; r < 4; r++) {
            float vmax = -1e30f;
#pragma unroll
            for (int nt = 0; nt < 4; nt++) {
                float sv = s[nt][r] * scale;
                if (needmask && (keybase + nt * 16 + l15) > (hist + rowbase + r))
                    sv = -1e30f;
                p[nt][r] = sv;
                vmax = fmaxf(vmax, sv);
            }
            for (int off = 1; off < 16; off <<= 1)
                vmax = fmaxf(vmax, __shfl_xor(vmax, off, 64));
            float mn = fmaxf(mstate[r], vmax);
            float al = __expf(mstate[r] - mn);
            mstate[r] = mn;
            float rs = 0.f;
#pragma unroll
            for (int nt = 0; nt < 4; nt++) {
                float pe = __expf(p[nt][r] - mn);
                p[nt][r] = pe; rs += pe;
            }
            for (int off = 1; off < 16; off <<= 1)
                rs += __shfl_xor(rs, off, 64);
            lstate[r] = lstate[r] * al + rs;
#pragma unroll
            for (int dt = 0; dt < 8; dt++) o[dt][r] *= al;
        }
        // P -> LDS (wave-private, C-layout -> A-layout round trip)
#pragma unroll
        for (int nt = 0; nt < 4; nt++) {
            int n = nt * 16 + l15;
#pragma unroll
            for (int r = 0; r < 4; r++)
                Ps[w * 1024 + (n >> 5) * 512 + (qd * 4 + r) * 32 + (n & 31)] = f2bf(p[nt][r]);
        }
        // O += P V
#pragma unroll
        for (int ks2 = 0; ks2 < 2; ks2++) {
            bf16x8 ap = *(const bf16x8*)&Ps[w * 1024 + ks2 * 512 + l15 * 32 + qd * 8];
#pragma unroll
            for (int dt = 0; dt < 8; dt++) {
                bf16x8 bv = *(const bf16x8*)&Vt[ks2 * 4096 + (dt * 16 + l15) * 32 + qd * 8];
                o[dt] = __builtin_amdgcn_mfma_f32_16x16x32_bf16(ap, bv, o[dt], 0, 0, 0);
            }
        }
    }
#pragma unroll
    for (int dt = 0; dt < 8; dt++) {
        int d = dt * 16 + l15;
#pragma unroll
        for (int r = 0; r < 4; r++) {
            int token = tok0 + w * 16 + qd * 4 + r;
            aout[((long)token * N_HEADS + h) * HD + d] = f2bf(o[dt][r] / lstate[r]);
        }
    }
}

// ------------------------------------------------------------------------ launch
extern "C" void kernel_launch(void* const* d_in, const int* in_sizes, int n_in,
                              void* d_out, int out_size, void* d_ws, size_t ws_size,
                              hipStream_t stream)
{
    const float* H   = (const float*)d_in[0];
    const int* pos   = (const int*)d_in[1];
    const int* qst   = (const int*)d_in[2];
    const int* qln   = (const int*)d_in[3];
    const int* kvln  = (const int*)d_in[4];
    const int* boff  = (const int*)d_in[5];
    float* pk        = (float*)d_in[6];
    float* pv        = (float*)d_in[7];
    const float* Wq  = (const float*)d_in[8];
    const float* bq  = (const float*)d_in[9];
    const float* Wk  = (const float*)d_in[10];
    const float* bk  = (const float*)d_in[11];
    const float* Wv  = (const float*)d_in[12];
    const float* bv  = (const float*)d_in[13];
    const float* Wo  = (const float*)d_in[14];
    const float* bo  = (const float*)d_in[15];
    float* out = (float*)d_out;

    int T    = in_sizes[0] / HIDDEN;   // 3072
    int Bn   = in_sizes[2];            // 4
    int maxb = in_sizes[5] / Bn;       // 24

    char* p = (char*)d_ws;
    u16* wsW   = (u16*)p;  p += (long)3 * HIDDEN * HIDDEN * 2;  // Wq|Wk|Wv bf16 [12288,4096]
    u16* wsWo  = (u16*)p;  p += (long)HIDDEN * HIDDEN * 2;
    u16* wsH   = (u16*)p;  p += (long)T * HIDDEN * 2;
    u16* wsQKV = (u16*)p;  p += (long)T * 3 * HIDDEN * 2;
    u16* wsQr  = (u16*)p;  p += (long)T * HIDDEN * 2;
    u16* wsAO  = (u16*)p;  p += (long)T * HIDDEN * 2;
    float* wsB = (float*)p;

    cast_kernel<<<2048, 256, 0, stream>>>(Wq, Wk, Wv, Wo, H, bq, bk, bv,
                                          wsW, wsWo, wsH, wsB, (long)T * HIDDEN);
    dim3 g1(T / 128, (3 * HIDDEN) / 128);
    gemm_bt<<<g1, 256, 0, stream>>>(wsH, wsW, wsB, wsQKV, T, 3 * HIDDEN, HIDDEN, 1);
    rope_scatter<<<T * 8, 256, 0, stream>>>(wsQKV, pos, qst, qln, kvln, boff,
                                            pk, pv, wsQr, Bn, maxb);
    int ntiles = T / 64;  // 48
    attn_kernel<<<ntiles * N_HEADS, 256, 0, stream>>>(wsQr, pk, pv, qst, qln, kvln,
                                                      boff, wsAO, Bn, maxb, ntiles);
    dim3 g2(T / 128, HIDDEN / 128);
    gemm_bt<<<g2, 256, 0, stream>>>(wsAO, wsWo, bo, out, T, HIDDEN, HIDDEN, 0);
}

// Round 2
// 1223.988 us; speedup vs baseline: 1.2223x; 1.2223x over previous
//
#include <hip/hip_runtime.h>
#include <hip/hip_bf16.h>

typedef unsigned short u16;
typedef __bf16 bf16x8 __attribute__((ext_vector_type(8)));
typedef short s16x4 __attribute__((ext_vector_type(4)));
typedef float f32x4 __attribute__((ext_vector_type(4)));

#define N_HEADS 32
#define HD 128
#define HIDDEN 4096

__device__ __forceinline__ u16 f2bf(float x) {
    union { float f; unsigned u; } v; v.f = x;
    unsigned r = v.u + 0x7fffu + ((v.u >> 16) & 1u);
    return (u16)(r >> 16);
}
__device__ __forceinline__ float bf2f(u16 x) {
    return __uint_as_float((unsigned)x << 16);
}
// pack two fp32 -> two bf16 (round-half-up) in one dword
__device__ __forceinline__ unsigned pack_bf16(float a, float b) {
    unsigned ua = __float_as_uint(a) + 0x8000u;
    unsigned ub = __float_as_uint(b) + 0x8000u;
    return __builtin_amdgcn_perm(ub, ua, 0x07060302);
}
__device__ __forceinline__ void gload_lds16(const void* g, void* l) {
    __builtin_amdgcn_global_load_lds(
        (const __attribute__((address_space(1))) unsigned*)g,
        (__attribute__((address_space(3))) unsigned*)l, 16, 0, 0);
}

// ---------------------------------------------------------------- cast kernel
__global__ __launch_bounds__(256) void cast_kernel(
    const float* __restrict__ Wq, const float* __restrict__ Wk,
    const float* __restrict__ Wv, const float* __restrict__ Wo,
    const float* __restrict__ H,
    const float* __restrict__ bq, const float* __restrict__ bk,
    const float* __restrict__ bv,
    u16* __restrict__ wsW, u16* __restrict__ wsWo, u16* __restrict__ wsH,
    float* __restrict__ wsB, long hsz)
{
    const long WSZ = (long)HIDDEN * HIDDEN;
    long total4 = (WSZ * 4 + hsz) >> 2;
    for (long i = (long)blockIdx.x * blockDim.x + threadIdx.x; i < total4;
         i += (long)gridDim.x * blockDim.x) {
        long e = i << 2;
        const float* src; u16* dst;
        if (e < WSZ)            { src = Wq + e;           dst = wsW + e; }
        else if (e < 2*WSZ)     { src = Wk + (e - WSZ);   dst = wsW + e; }
        else if (e < 3*WSZ)     { src = Wv + (e - 2*WSZ); dst = wsW + e; }
        else if (e < 4*WSZ)     { src = Wo + (e - 3*WSZ); dst = wsWo + (e - 3*WSZ); }
        else                    { src = H  + (e - 4*WSZ); dst = wsH  + (e - 4*WSZ); }
        float4 v = *(const float4*)src;
        ushort4 o; o.x = f2bf(v.x); o.y = f2bf(v.y); o.z = f2bf(v.z); o.w = f2bf(v.w);
        *(ushort4*)dst = o;
    }
    for (int i = blockIdx.x * blockDim.x + threadIdx.x; i < 3 * HIDDEN;
         i += gridDim.x * blockDim.x) {
        wsB[i] = (i < HIDDEN) ? bq[i] : (i < 2*HIDDEN ? bk[i - HIDDEN] : bv[i - 2*HIDDEN]);
    }
}

// ------------------------------------------------- GEMM: C[M,N] = A @ Bt^T + bias
__global__ __launch_bounds__(256) void gemm_bt(
    const u16* __restrict__ A, const u16* __restrict__ Bt,
    const float* __restrict__ bias, void* __restrict__ Cout,
    int M, int N, int K, int out_bf16)
{
    __shared__ u16 As[128 * 32];
    __shared__ u16 Bs[128 * 32];
    const int tid = threadIdx.x;
    const int w = tid >> 6, lane = tid & 63;
    const int qd = lane >> 4, l15 = lane & 15;
    const int bm = blockIdx.x, bn = blockIdx.y;
    const int wm = w >> 1, wn = w & 1;
    f32x4 acc[4][4] = {};
    const int srow = lane >> 2;
    const int scol = (lane & 3) * 8;
    const long Ar = (long)bm * 128 + w * 32 + srow;
    const long Br = (long)bn * 128 + w * 32 + srow;
    for (int k0 = 0; k0 < K; k0 += 32) {
        __syncthreads();
        gload_lds16(A  + Ar * K        + k0 + scol, (char*)As + (w*32     ) * 64);
        gload_lds16(A  + (Ar + 16) * K + k0 + scol, (char*)As + (w*32 + 16) * 64);
        gload_lds16(Bt + Br * K        + k0 + scol, (char*)Bs + (w*32     ) * 64);
        gload_lds16(Bt + (Br + 16) * K + k0 + scol, (char*)Bs + (w*32 + 16) * 64);
        __syncthreads();
        bf16x8 a[4], b[4];
#pragma unroll
        for (int mt = 0; mt < 4; mt++)
            a[mt] = *(const bf16x8*)&As[(wm*64 + mt*16 + l15) * 32 + qd * 8];
#pragma unroll
        for (int nt = 0; nt < 4; nt++)
            b[nt] = *(const bf16x8*)&Bs[(wn*64 + nt*16 + l15) * 32 + qd * 8];
#pragma unroll
        for (int mt = 0; mt < 4; mt++)
#pragma unroll
            for (int nt = 0; nt < 4; nt++)
                acc[mt][nt] = __builtin_amdgcn_mfma_f32_16x16x32_bf16(
                    a[mt], b[nt], acc[mt][nt], 0, 0, 0);
    }
#pragma unroll
    for (int nt = 0; nt < 4; nt++) {
        int n = bn*128 + wn*64 + nt*16 + l15;
        float bv = bias[n];
#pragma unroll
        for (int mt = 0; mt < 4; mt++) {
            int m0 = bm*128 + wm*64 + mt*16 + qd*4;
#pragma unroll
            for (int r = 0; r < 4; r++) {
                float v = acc[mt][nt][r] + bv;
                if (out_bf16) ((u16*)Cout)[(long)(m0 + r) * N + n] = f2bf(v);
                else          ((float*)Cout)[(long)(m0 + r) * N + n] = v;
            }
        }
    }
}

// ------------------------------------------------- RoPE in place on wsQKV (Q & K)
// Q additionally pre-scaled by 1/sqrt(HD).
__global__ __launch_bounds__(256) void rope_inplace(
    u16* __restrict__ qkv, const int* __restrict__ pos_ids)
{
    int t = blockIdx.x >> 3;
    int h = ((blockIdx.x & 7) << 2) + (threadIdx.x >> 6);
    int d = threadIdx.x & 63;
    int pos = pos_ids[t];
    float inv = exp2f(-(float)d * (13.287712379549449f / 64.0f));
    float f = (float)pos * inv;
    float cs = cosf(f), sn = sinf(f);
    const float qscale = 0.08838834764831845f;
    u16* row = qkv + (long)t * (3 * HIDDEN);
    float q1 = bf2f(row[h*HD + d]);
    float q2 = bf2f(row[h*HD + d + 64]);
    row[h*HD + d]      = f2bf((q1 * cs - q2 * sn) * qscale);
    row[h*HD + d + 64] = f2bf((q2 * cs + q1 * sn) * qscale);
    float k1 = bf2f(row[HIDDEN + h*HD + d]);
    float k2 = bf2f(row[HIDDEN + h*HD + d + 64]);
    row[HIDDEN + h*HD + d]      = f2bf(k1 * cs - k2 * sn);
    row[HIDDEN + h*HD + d + 64] = f2bf(k2 * cs + k1 * sn);
}

// ------------------------------------- build bf16 KV in attention-ready layouts
// Kc: [blk][h][ks(4)][key(64)][32d]   (16KB per (blk,h), == LDS image)
// Vc: [blk][h][d(128)][72key-padded]  (18KB per (blk,h), == LDS image)
__global__ __launch_bounds__(256) void kvtransform(
    const float* __restrict__ pk, const float* __restrict__ pv,
    const u16* __restrict__ qkv,
    const int* __restrict__ q_start, const int* __restrict__ q_lens,
    const int* __restrict__ kv_lens, const int* __restrict__ blk_off,
    u16* __restrict__ Kc, u16* __restrict__ Vc, int maxb)
{
    int b = blockIdx.x / maxb, c = blockIdx.x % maxb;
    int h = blockIdx.y;
    int kvlen = kv_lens[b];
    if (c * 64 >= kvlen) return;
    int hist = kvlen - q_lens[b];
    int t0 = q_start[b];
    int blk = blk_off[b * maxb + c];
    const int tid = threadIdx.x;
    u16* kout = Kc + ((long)blk * N_HEADS + h) * 8192;
    u16* vout = Vc + ((long)blk * N_HEADS + h) * 9216;
    // K: out elem linear = ks*2048 + key*32 + quad*4 (+0..3)
#pragma unroll
    for (int r = 0; r < 8; r++) {
        int i = r * 256 + tid;
        int quad = i & 7, key = (i >> 3) & 63, ks = i >> 9;
        int kvpos = c * 64 + key;
        ushort4 o4;
        if (kvpos < hist) {
            float4 f = *(const float4*)(pk + (((long)blk*64 + key)*N_HEADS + h)*HD
                                           + ks*32 + quad*4);
            o4.x = f2bf(f.x); o4.y = f2bf(f.y); o4.z = f2bf(f.z); o4.w = f2bf(f.w);
        } else {
            int tok = t0 + kvpos - hist;
            o4 = *(const ushort4*)(qkv + (long)tok*(3*HIDDEN) + HIDDEN
                                      + h*HD + ks*32 + quad*4);
        }
        *(ushort4*)(kout + (long)i * 4) = o4;
    }
    // V transposed: out row d has 64 keys (+8 pad), thread handles 4 keys of one d
#pragma unroll
    for (int r = 0; r < 8; r++) {
        int i = r * 256 + tid;
        int kq = i & 15, d = i >> 4;
        ushort4 o4; u16* o = (u16*)&o4;
#pragma unroll
        for (int j = 0; j < 4; j++) {
            int key = kq * 4 + j;
            int kvpos = c * 64 + key;
            if (kvpos < hist)
                o[j] = f2bf(pv[(((long)blk*64 + key)*N_HEADS + h)*HD + d]);
            else {
                int tok = t0 + kvpos - hist;
                o[j] = qkv[(long)tok*(3*HIDDEN) + 2*HIDDEN + h*HD + d];
            }
        }
        *(ushort4*)(vout + (long)d * 72 + kq * 4) = o4;
    }
}

// ----------------------------------------------------- flash attention (paged KV)
__global__ __launch_bounds__(256, 4) void attn_kernel(
    const u16* __restrict__ qkv, const u16* __restrict__ Kc,
    const u16* __restrict__ Vc,
    const int* __restrict__ q_start, const int* __restrict__ q_lens,
    const int* __restrict__ kv_lens, const int* __restrict__ blk_off,
    u16* __restrict__ aout, int Bn, int maxb, int ntiles)
{
    __shared__ u16 Ks[4 * 64 * 32];   // [ks][key][32d]  16KB
    __shared__ u16 Vt[128 * 72];      // [d][72key]      18KB
    int tile = ntiles - 1 - (blockIdx.x % ntiles);   // heavy tiles first
    int h    = blockIdx.x / ntiles;
    int b = 0, q0 = 0, acc = 0;
    for (int i = 0; i < Bn; i++) {
        int nt = q_lens[i] >> 6;
        if (tile >= acc && tile < acc + nt) { b = i; q0 = (tile - acc) << 6; }
        acc += nt;
    }
    int hist = kv_lens[b] - q_lens[b];
    int tok0 = q_start[b] + q0;
    int nchunk = (hist + q0 + 63) / 64 + 1;
    const int tid = threadIdx.x, w = tid >> 6, lane = tid & 63;
    const int qd = lane >> 4, l15 = lane & 15;

    // Q fragments for this wave's 16 rows: B-frag of S^T mfma (n=l15 -> q row)
    const u16* qrow = qkv + (long)(tok0 + w*16 + l15) * (3*HIDDEN) + h * HD;
    bf16x8 qf[4];
#pragma unroll
    for (int ds = 0; ds < 4; ds++)
        qf[ds] = *(const bf16x8*)(qrow + ds*32 + qd*8);

    f32x4 o[8] = {};
    f32x4 lsum = {};
    const s16x4 ONES = { (short)0x3F80, (short)0x3F80, (short)0x3F80, (short)0x3F80 };
    const int qglob = hist + q0 + w*16 + l15;   // absolute position of this q row

    for (int c = 0; c < nchunk; c++) {
        int blk = blk_off[b * maxb + c];
        const u16* kg_ = Kc + ((long)blk * N_HEADS + h) * 8192;
        const u16* vg_ = Vc + ((long)blk * N_HEADS + h) * 9216;
        __syncthreads();
#pragma unroll
        for (int r = 0; r < 4; r++) {
            int idx = r*256 + w*64 + lane;
            gload_lds16(kg_ + idx*8, Ks + idx*8);
        }
#pragma unroll
        for (int r = 0; r < 4; r++) {
            int idx = r*256 + w*64 + lane;
            gload_lds16(vg_ + idx*8, Vt + idx*8);
        }
        if (w < 2) {
            int idx = 1024 + w*64 + lane;
            gload_lds16(vg_ + idx*8, Vt + idx*8);
        }
        __syncthreads();
        // S^T = K·Q^T : s[kg] C-layout: q=l15, key = kg*16 + qd*4 + r
        f32x4 s[4] = {};
#pragma unroll
        for (int ds = 0; ds < 4; ds++)
#pragma unroll
            for (int kg = 0; kg < 4; kg++) {
                bf16x8 a = *(const bf16x8*)&Ks[ds*2048 + (kg*16 + l15)*32 + qd*8];
                s[kg] = __builtin_amdgcn_mfma_f32_16x16x32_bf16(a, qf[ds], s[kg], 0, 0, 0);
            }
        bool needmask = (c*64 + 63) > (hist + q0 + w*16);
#pragma unroll
        for (int kg = 0; kg < 4; kg++) {
            int keyb = c*64 + kg*16 + qd*4;
            float pe0, pe1, pe2, pe3;
            if (needmask) {
                int thr = qglob - keyb;   // allow r <= thr
                pe0 = __expf(0 <= thr ? s[kg][0] : -1e30f);
                pe1 = __expf(1 <= thr ? s[kg][1] : -1e30f);
                pe2 = __expf(2 <= thr ? s[kg][2] : -1e30f);
                pe3 = __expf(3 <= thr ? s[kg][3] : -1e30f);
            } else {
                pe0 = __expf(s[kg][0]); pe1 = __expf(s[kg][1]);
                pe2 = __expf(s[kg][2]); pe3 = __expf(s[kg][3]);
            }
            union { unsigned u[2]; s16x4 v; } pu;
            pu.u[0] = pack_bf16(pe0, pe1);
            pu.u[1] = pack_bf16(pe2, pe3);
            s16x4 p4 = pu.v;
            lsum = __builtin_amdgcn_mfma_f32_16x16x16bf16_1k(p4, ONES, lsum, 0, 0, 0);
#pragma unroll
            for (int dt = 0; dt < 8; dt++) {
                s16x4 b4 = *(const s16x4*)&Vt[(dt*16 + l15)*72 + kg*16 + qd*4];
                o[dt] = __builtin_amdgcn_mfma_f32_16x16x16bf16_1k(p4, b4, o[dt], 0, 0, 0);
            }
        }
    }
    float inv[4];
#pragma unroll
    for (int r = 0; r < 4; r++) inv[r] = 1.0f / lsum[r];
#pragma unroll
    for (int dt = 0; dt < 8; dt++) {
        int d = dt*16 + l15;
#pragma unroll
        for (int r = 0; r < 4; r++) {
            int token = tok0 + w*16 + qd*4 + r;
            aout[((long)token * N_HEADS + h) * HD + d] = f2bf(o[dt][r] * inv[r]);
        }
    }
}

// ------------------------------------------------------------------------ launch
extern "C" void kernel_launch(void* const* d_in, const int* in_sizes, int n_in,
                              void* d_out, int out_size, void* d_ws, size_t ws_size,
                              hipStream_t stream)
{
    const float* H   = (const float*)d_in[0];
    const int* pos   = (const int*)d_in[1];
    const int* qst   = (const int*)d_in[2];
    const int* qln   = (const int*)d_in[3];
    const int* kvln  = (const int*)d_in[4];
    const int* boff  = (const int*)d_in[5];
    const float* pk  = (const float*)d_in[6];
    const float* pv  = (const float*)d_in[7];
    const float* Wq  = (const float*)d_in[8];
    const float* bq  = (const float*)d_in[9];
    const float* Wk  = (const float*)d_in[10];
    const float* bk  = (const float*)d_in[11];
    const float* Wv  = (const float*)d_in[12];
    const float* bv  = (const float*)d_in[13];
    const float* Wo  = (const float*)d_in[14];
    const float* bo  = (const float*)d_in[15];
    float* out = (float*)d_out;

    int T    = in_sizes[0] / HIDDEN;      // 3072
    int Bn   = in_sizes[2];               // 4
    int maxb = in_sizes[5] / Bn;          // 24
    int NBLK = in_sizes[6] / (64 * N_HEADS * HD);   // 96

    char* p = (char*)d_ws;
    u16* wsW   = (u16*)p;  p += (long)3 * HIDDEN * HIDDEN * 2;
    u16* wsWo  = (u16*)p;  p += (long)HIDDEN * HIDDEN * 2;
    u16* wsH   = (u16*)p;  p += (long)T * HIDDEN * 2;
    u16* wsQKV = (u16*)p;  p += (long)T * 3 * HIDDEN * 2;
    u16* wsAO  = (u16*)p;  p += (long)T * HIDDEN * 2;
    u16* wsKc  = (u16*)p;  p += (long)NBLK * N_HEADS * 8192 * 2;
    u16* wsVc  = (u16*)p;  p += (long)NBLK * N_HEADS * 9216 * 2;
    float* wsB = (float*)p;

    cast_kernel<<<2048, 256, 0, stream>>>(Wq, Wk, Wv, Wo, H, bq, bk, bv,
                                          wsW, wsWo, wsH, wsB, (long)T * HIDDEN);
    dim3 g1(T / 128, (3 * HIDDEN) / 128);
    gemm_bt<<<g1, 256, 0, stream>>>(wsH, wsW, wsB, wsQKV, T, 3 * HIDDEN, HIDDEN, 1);
    rope_inplace<<<T * 8, 256, 0, stream>>>(wsQKV, pos);
    dim3 g2(Bn * maxb, N_HEADS);
    kvtransform<<<g2, 256, 0, stream>>>(pk, pv, wsQKV, qst, qln, kvln, boff,
                                        wsKc, wsVc, maxb);
    int ntiles = T / 64;
    attn_kernel<<<ntiles * N_HEADS, 256, 0, stream>>>(wsQKV, wsKc, wsVc, qst, qln,
                                                      kvln, boff, wsAO, Bn, maxb, ntiles);
    dim3 g3(T / 128, HIDDEN / 128);
    gemm_bt<<<g3, 256, 0, stream>>>(wsAO, wsWo, bo, out, T, HIDDEN, HIDDEN, 0);
}